// Round 5
// baseline (576.478 us; speedup 1.0000x reference)
//
#include <hip/hip_runtime.h>

// Problem constants (from reference): texture [1024,1024,17] f32, uv [N,2] f32.
// Outputs flat: values (N*16) || homogeneous (N*1) || vnn (N*17).
#define TEX_H 1024
#define TEX_W 1024
#define TEX_C 17

// 4B-aligned true-vector types: row base is (y*1024+x)*68 bytes -> only 4B
// aligned, so dwordx4 loads must be declared aligned(4). gfx950 global loads
// only require dword alignment for multi-dword widths.
typedef float v4fa4 __attribute__((ext_vector_type(4), aligned(4)));
typedef float v2fa4 __attribute__((ext_vector_type(2), aligned(4)));

// Load 34 contiguous floats (one row-pair t0x: t00[0..16] || t01[0..16]) with
// 9 VMEM instructions (8x dwordx4 + 1x dwordx2) instead of 34 scalar gathers.
// The kernel is TA address-rate bound: each divergent wave64 VMEM instr costs
// ~64 address slots regardless of width, so wider loads are ~4x cheaper/byte.
__device__ __forceinline__ void load_row34(const float* __restrict__ r, float* d) {
#pragma unroll
    for (int q = 0; q < 4; ++q) {
        v4fa4 t = *(const v4fa4*)(r + q * 4);
        d[q * 4 + 0] = t.x; d[q * 4 + 1] = t.y;
        d[q * 4 + 2] = t.z; d[q * 4 + 3] = t.w;
    }
    v2fa4 m = *(const v2fa4*)(r + 16);   // floats 16,17 = t00[16] || t01[0]
    d[16] = m.x; d[17] = m.y;
#pragma unroll
    for (int q = 0; q < 4; ++q) {
        v4fa4 t = *(const v4fa4*)(r + 18 + q * 4);
        d[18 + q * 4 + 0] = t.x; d[18 + q * 4 + 1] = t.y;
        d[18 + q * 4 + 2] = t.z; d[18 + q * 4 + 3] = t.w;
    }
}

__global__ __launch_bounds__(256) void slice_texture_kernel(
    const float* __restrict__ tex,
    const float* __restrict__ uv,
    float* __restrict__ out,
    int n)
{
    int i = blockIdx.x * blockDim.x + threadIdx.x;
    if (i >= n) return;

    // Coalesced 8B/lane uv load.
    float2 p = ((const float2*)uv)[i];

    float x = p.x * (float)(TEX_W - 1);
    float y = p.y * (float)(TEX_H - 1);
    float x0f = fminf(fmaxf(floorf(x), 0.0f), (float)(TEX_W - 2));
    float y0f = fminf(fmaxf(floorf(y), 0.0f), (float)(TEX_H - 2));
    int x0 = (int)x0f;
    int y0 = (int)y0f;
    float fx = x - x0f;
    float fy = y - y0f;
    float gx = 1.0f - fx;
    float gy = 1.0f - fy;

    const float* r0 = tex + ((size_t)y0 * TEX_W + (size_t)x0) * TEX_C;
    const float* r1 = r0 + (size_t)TEX_W * TEX_C;

    // Issue both row-pair loads up front (18 wide VMEM ops in flight), then
    // interpolate. row arrays are statically indexed -> stay in VGPRs.
    float row0[34], row1[34];
    load_row34(r0, row0);
    load_row34(r1, row1);

    float vnn[TEX_C];
#pragma unroll
    for (int c = 0; c < TEX_C; ++c) {
        float top = row0[c] * gx + row0[c + 17] * fx;
        float bot = row1[c] * gx + row1[c + 17] * fx;
        vnn[c] = top * gy + bot * fy;
    }

    float h = vnn[16];
    float inv = 1.0f / (h + 1e-5f);   // exact div once; 2% absmax threshold makes rounding moot

    // values: rows of 16 floats = 64B, 16B-aligned -> 4x float4 stores.
    float4* vrow = (float4*)(out + (size_t)i * 16);
#pragma unroll
    for (int q = 0; q < 4; ++q) {
        float4 v;
        v.x = vnn[q * 4 + 0] * inv;
        v.y = vnn[q * 4 + 1] * inv;
        v.z = vnn[q * 4 + 2] * inv;
        v.w = vnn[q * 4 + 3] * inv;
        vrow[q] = v;
    }

    // homogeneous: perfectly coalesced scalar store.
    out[(size_t)n * 16 + i] = h;

    // vnn: rows of 17 floats (68B, 4B-aligned) -> 4x dwordx4 + 1 scalar.
    float* vout = out + (size_t)n * 17 + (size_t)i * 17;
#pragma unroll
    for (int q = 0; q < 4; ++q) {
        v4fa4 v;
        v.x = vnn[q * 4 + 0]; v.y = vnn[q * 4 + 1];
        v.z = vnn[q * 4 + 2]; v.w = vnn[q * 4 + 3];
        *(v4fa4*)(vout + q * 4) = v;
    }
    vout[16] = vnn[16];
}

extern "C" void kernel_launch(void* const* d_in, const int* in_sizes, int n_in,
                              void* d_out, int out_size, void* d_ws, size_t ws_size,
                              hipStream_t stream) {
    const float* tex = (const float*)d_in[0];
    const float* uv  = (const float*)d_in[1];
    float* out = (float*)d_out;
    int n = in_sizes[1] / 2;  // N points

    const int block = 256;
    const int grid = (n + block - 1) / block;
    slice_texture_kernel<<<grid, block, 0, stream>>>(tex, uv, out, n);
}

// Round 6
// 566.984 us; speedup vs baseline: 1.0167x; 1.0167x over previous
//
#include <hip/hip_runtime.h>

// Problem constants (from reference): texture [1024,1024,17] f32, uv [N,2] f32.
// Outputs flat: values (N*16) || homogeneous (N*1) || vnn (N*17).
#define TEX_H 1024
#define TEX_W 1024
#define TEX_C 17

// 4B-aligned true-vector types: row base is (y*1024+x)*68 bytes -> only 4B
// aligned, so dwordx4 loads must be declared aligned(4).
typedef float v4fa4 __attribute__((ext_vector_type(4), aligned(4)));
typedef float v2fa4 __attribute__((ext_vector_type(2), aligned(4)));

// Load 34 contiguous floats (one row-pair t00||t01) with 9 VMEM instructions
// (8x dwordx4 + 1x dwordx2) instead of 34 scalar gathers — removes the TA
// address-issue floor (~220us) of the scalar variant.
__device__ __forceinline__ void load_row34(const float* __restrict__ r, float* d) {
#pragma unroll
    for (int q = 0; q < 4; ++q) {
        v4fa4 t = *(const v4fa4*)(r + q * 4);
        d[q * 4 + 0] = t.x; d[q * 4 + 1] = t.y;
        d[q * 4 + 2] = t.z; d[q * 4 + 3] = t.w;
    }
    v2fa4 m = *(const v2fa4*)(r + 16);   // floats 16,17 = t00[16] || t01[0]
    d[16] = m.x; d[17] = m.y;
#pragma unroll
    for (int q = 0; q < 4; ++q) {
        v4fa4 t = *(const v4fa4*)(r + 18 + q * 4);
        d[18 + q * 4 + 0] = t.x; d[18 + q * 4 + 1] = t.y;
        d[18 + q * 4 + 2] = t.z; d[18 + q * 4 + 3] = t.w;
    }
}

// OCCUPANCY CAP: dur tracks hbm_bytes/3.7TB/s in every measured config; fetch
// volume is set by (in-flight random working set) vs L3. Round-5's 72% occ
// (23 waves/CU) blew the working set past the 256MB MALL -> zero texture
// reuse (946MB fetch). Cap to 3 blocks/CU (12 waves/CU) via 48KB dynamic LDS
// so texture lines survive between touches.
#define LDS_CAP_BYTES (48 * 1024)

__global__ __launch_bounds__(256) void slice_texture_kernel(
    const float* __restrict__ tex,
    const float* __restrict__ uv,
    float* __restrict__ out,
    int n)
{
    int i = blockIdx.x * blockDim.x + threadIdx.x;
    if (i >= n) return;

    // Coalesced 8B/lane uv load.
    float2 p = ((const float2*)uv)[i];

    float x = p.x * (float)(TEX_W - 1);
    float y = p.y * (float)(TEX_H - 1);
    float x0f = fminf(fmaxf(floorf(x), 0.0f), (float)(TEX_W - 2));
    float y0f = fminf(fmaxf(floorf(y), 0.0f), (float)(TEX_H - 2));
    int x0 = (int)x0f;
    int y0 = (int)y0f;
    float fx = x - x0f;
    float fy = y - y0f;
    float gx = 1.0f - fx;
    float gy = 1.0f - fy;

    const float* r0 = tex + ((size_t)y0 * TEX_W + (size_t)x0) * TEX_C;
    const float* r1 = r0 + (size_t)TEX_W * TEX_C;

    // Issue both row-pair loads up front, then interpolate. Statically
    // indexed -> stays in VGPRs.
    float row0[34], row1[34];
    load_row34(r0, row0);
    load_row34(r1, row1);

    float vnn[TEX_C];
#pragma unroll
    for (int c = 0; c < TEX_C; ++c) {
        float top = row0[c] * gx + row0[c + 17] * fx;
        float bot = row1[c] * gx + row1[c + 17] * fx;
        vnn[c] = top * gy + bot * fy;
    }

    float h = vnn[16];
    float inv = 1.0f / (h + 1e-5f);   // exact div once; 2% absmax threshold makes rounding moot

    // values: rows of 16 floats = 64B, 16B-aligned -> 4x float4 stores.
    float4* vrow = (float4*)(out + (size_t)i * 16);
#pragma unroll
    for (int q = 0; q < 4; ++q) {
        float4 v;
        v.x = vnn[q * 4 + 0] * inv;
        v.y = vnn[q * 4 + 1] * inv;
        v.z = vnn[q * 4 + 2] * inv;
        v.w = vnn[q * 4 + 3] * inv;
        vrow[q] = v;
    }

    // homogeneous: perfectly coalesced scalar store.
    out[(size_t)n * 16 + i] = h;

    // vnn: rows of 17 floats (68B, 4B-aligned) -> 4x dwordx4 + 1 scalar.
    float* vout = out + (size_t)n * 17 + (size_t)i * 17;
#pragma unroll
    for (int q = 0; q < 4; ++q) {
        v4fa4 v;
        v.x = vnn[q * 4 + 0]; v.y = vnn[q * 4 + 1];
        v.z = vnn[q * 4 + 2]; v.w = vnn[q * 4 + 3];
        *(v4fa4*)(vout + q * 4) = v;
    }
    vout[16] = vnn[16];
}

extern "C" void kernel_launch(void* const* d_in, const int* in_sizes, int n_in,
                              void* d_out, int out_size, void* d_ws, size_t ws_size,
                              hipStream_t stream) {
    const float* tex = (const float*)d_in[0];
    const float* uv  = (const float*)d_in[1];
    float* out = (float*)d_out;
    int n = in_sizes[1] / 2;  // N points

    const int block = 256;
    const int grid = (n + block - 1) / block;
    // 48KB dynamic LDS per block: floor(160/48)=3 blocks/CU = 12 waves/CU.
    slice_texture_kernel<<<grid, block, LDS_CAP_BYTES, stream>>>(tex, uv, out, n);
}